// Round 6
// baseline (18900.215 us; speedup 1.0000x reference)
//
#include <hip/hip_runtime.h>
#include <hip/hip_bf16.h>

// Problem constants
#define BB 128
#define TT 512
#define FF 256
#define CC 1024
#define KO 256

// Geometry: 256 blocks = 8 b-tiles (16 rows) x 32 c-tiles (32 channels).
// 512 threads = 32 cl (channel) x 16 ks (K-split slice).
// All weights register-resident: thread holds W columns for its (c, k-slice).
#define NBLK 256
#define NTHR 512

__device__ __forceinline__ float tanh_fast(float v) {
  // tanh(v) = 1 - 2/(e^{2v}+1); exact at +-inf, ~1e-7 error elsewhere.
  const float e = __expf(2.f * v);
  return 1.f - 2.f / (e + 1.f);
}

// ---------------------------------------------------------------------------
// Group barrier: the 32 blocks sharing one b-tile (h rows are b-disjoint
// across groups, so only same-b-tile blocks need to sync). Slot per timestep,
// counters zeroed each launch -> no sense reversal.
// ---------------------------------------------------------------------------
__device__ __forceinline__ void group_barrier(int* __restrict__ cnt, int slot,
                                              int btile) {
  __syncthreads();
  if (threadIdx.x == 0) {
    __threadfence();  // release: this block's h writes device-visible
    __hip_atomic_fetch_add(&cnt[slot * 8 + btile], 1, __ATOMIC_ACQ_REL,
                           __HIP_MEMORY_SCOPE_AGENT);
    while (__hip_atomic_load(&cnt[slot * 8 + btile], __ATOMIC_ACQUIRE,
                             __HIP_MEMORY_SCOPE_AGENT) < 32) {
      __builtin_amdgcn_s_sleep(1);
    }
    __threadfence();  // acquire: invalidate stale L1 before reading peers' h
  }
  __syncthreads();
}

// ---------------------------------------------------------------------------
// h_t = tanh(u_t * tanh(g_t));  u = x@Wu+bu, g = [x,h]@Wg+bg.
// (n/d/a_max are dead in the reference: never reassigned -> e_t cancels.)
// Runs [tstart, tend) steps. With tend-tstart==1 (fallback path) no barrier
// is ever executed, so co-residency is not required.
// ---------------------------------------------------------------------------
__global__ __launch_bounds__(NTHR, 2) void rwa_steps(
    const float* __restrict__ x,   // [B][T][F]
    const float* __restrict__ Wg,  // [F+C][C]
    const float* __restrict__ bg,  // [C]
    const float* __restrict__ Wu,  // [F][C]
    const float* __restrict__ bu,  // [C]
    float* __restrict__ hbuf,      // ws: [2][B][C]
    int* __restrict__ cnt,         // ws: [TT][8] barrier counters
    int tstart, int tend) {
  const int tid = threadIdx.x;
  const int bid = blockIdx.x;
  const int btile = bid >> 5;       // 0..7
  const int b0 = btile * 16;        // batch tile origin
  const int c0 = (bid & 31) * 32;   // channel tile origin
  const int cl = tid >> 4;          // 0..31 channel within tile
  const int ks = tid & 15;          // 0..15 K-slice
  const int c = c0 + cl;

  // ---- persistent weight registers (one-time, column-strided loads).
  // wh[i]: Wg h-part rows 256+4*(ks+16i)+j, col c.  96 floats/thread.
  float4 wh[16];
#pragma unroll
  for (int i = 0; i < 16; ++i) {
    const int k = 4 * (ks + 16 * i);
    wh[i].x = Wg[(size_t)(FF + k + 0) * CC + c];
    wh[i].y = Wg[(size_t)(FF + k + 1) * CC + c];
    wh[i].z = Wg[(size_t)(FF + k + 2) * CC + c];
    wh[i].w = Wg[(size_t)(FF + k + 3) * CC + c];
  }
  float4 wgx[4], wux[4];
#pragma unroll
  for (int i = 0; i < 4; ++i) {
    const int k = 4 * (ks + 16 * i);
    wgx[i].x = Wg[(size_t)(k + 0) * CC + c];
    wgx[i].y = Wg[(size_t)(k + 1) * CC + c];
    wgx[i].z = Wg[(size_t)(k + 2) * CC + c];
    wgx[i].w = Wg[(size_t)(k + 3) * CC + c];
    wux[i].x = Wu[(size_t)(k + 0) * CC + c];
    wux[i].y = Wu[(size_t)(k + 1) * CC + c];
    wux[i].z = Wu[(size_t)(k + 2) * CC + c];
    wux[i].w = Wu[(size_t)(k + 3) * CC + c];
  }
  const float bgv = bg[c];
  const float buv = bu[c];

  for (int t = tstart; t < tend; ++t) {
    const float* __restrict__ hp = hbuf + (size_t)(t & 1) * (BB * CC);
    float* __restrict__ hn = hbuf + (size_t)((t + 1) & 1) * (BB * CC);

    float accg[16], accu[16];
#pragma unroll
    for (int b = 0; b < 16; ++b) {
      accg[b] = 0.f;
      accu[b] = 0.f;
    }

    // ---- x-part (K=256): lanes ks 0..15 read consecutive quads -> coalesced
    const float* __restrict__ xb = x + (size_t)b0 * TT * FF + (size_t)t * FF;
#pragma unroll
    for (int i = 0; i < 4; ++i) {
      const int f = 4 * (ks + 16 * i);
#pragma unroll
      for (int b = 0; b < 16; ++b) {
        const float4 xq = *(const float4*)(xb + (size_t)b * TT * FF + f);
        accg[b] = fmaf(wgx[i].x, xq.x, accg[b]);
        accg[b] = fmaf(wgx[i].y, xq.y, accg[b]);
        accg[b] = fmaf(wgx[i].z, xq.z, accg[b]);
        accg[b] = fmaf(wgx[i].w, xq.w, accg[b]);
        accu[b] = fmaf(wux[i].x, xq.x, accu[b]);
        accu[b] = fmaf(wux[i].y, xq.y, accu[b]);
        accu[b] = fmaf(wux[i].z, xq.z, accu[b]);
        accu[b] = fmaf(wux[i].w, xq.w, accu[b]);
      }
    }

    // ---- h-part (K=1024): weight from registers, h quads from L1/L2
    const float* __restrict__ hb = hp + (size_t)b0 * CC;
#pragma unroll
    for (int i = 0; i < 16; ++i) {
      const int k = 4 * (ks + 16 * i);
#pragma unroll
      for (int b = 0; b < 16; ++b) {
        const float4 hq = *(const float4*)(hb + (size_t)b * CC + k);
        accg[b] = fmaf(wh[i].x, hq.x, accg[b]);
        accg[b] = fmaf(wh[i].y, hq.y, accg[b]);
        accg[b] = fmaf(wh[i].z, hq.z, accg[b]);
        accg[b] = fmaf(wh[i].w, hq.w, accg[b]);
      }
    }

    // ---- redistributing butterfly over the 16 ks-lanes: lane ks ends up
    // holding the full (g,u) sums for batch row b = ks. All register indices
    // compile-time (rule #20); shfl stays within the 16-lane group.
#pragma unroll
    for (int j = 0; j < 8; ++j) {
      const float sg = (ks & 8) ? accg[j] : accg[j + 8];
      const float su = (ks & 8) ? accu[j] : accu[j + 8];
      const float rg = __shfl_xor(sg, 8);
      const float ru = __shfl_xor(su, 8);
      accg[j] = ((ks & 8) ? accg[j + 8] : accg[j]) + rg;
      accu[j] = ((ks & 8) ? accu[j + 8] : accu[j]) + ru;
    }
#pragma unroll
    for (int j = 0; j < 4; ++j) {
      const float sg = (ks & 4) ? accg[j] : accg[j + 4];
      const float su = (ks & 4) ? accu[j] : accu[j + 4];
      const float rg = __shfl_xor(sg, 4);
      const float ru = __shfl_xor(su, 4);
      accg[j] = ((ks & 4) ? accg[j + 4] : accg[j]) + rg;
      accu[j] = ((ks & 4) ? accu[j + 4] : accu[j]) + ru;
    }
#pragma unroll
    for (int j = 0; j < 2; ++j) {
      const float sg = (ks & 2) ? accg[j] : accg[j + 2];
      const float su = (ks & 2) ? accu[j] : accu[j + 2];
      const float rg = __shfl_xor(sg, 2);
      const float ru = __shfl_xor(su, 2);
      accg[j] = ((ks & 2) ? accg[j + 2] : accg[j]) + rg;
      accu[j] = ((ks & 2) ? accu[j + 2] : accu[j]) + ru;
    }
    {
      const float sg = (ks & 1) ? accg[0] : accg[1];
      const float su = (ks & 1) ? accu[0] : accu[1];
      const float rg = __shfl_xor(sg, 1);
      const float ru = __shfl_xor(su, 1);
      accg[0] = ((ks & 1) ? accg[1] : accg[0]) + rg;
      accu[0] = ((ks & 1) ? accu[1] : accu[0]) + ru;
    }

    const float g = accg[0] + bgv;
    const float u = accu[0] + buv;
    const float hv = tanh_fast(u * tanh_fast(g));
    hn[(size_t)(b0 + ks) * CC + c] = hv;

    if (t + 1 < tend) group_barrier(cnt, t, btile);
  }
}

// ---- init: copy h0 -> hbuf[0] (256*512 == B*C exactly)
__global__ void rwa_init(const float* __restrict__ h0,
                         float* __restrict__ hbuf) {
  const int idx = blockIdx.x * NTHR + threadIdx.x;
  hbuf[idx] = h0[idx];
}

// ---- epilogue: out = h_T @ Wo + bo (h_T = hbuf[0], TT even)
__global__ __launch_bounds__(512) void rwa_out(const float* __restrict__ hT,
                                               const float* __restrict__ Wo,
                                               const float* __restrict__ bo,
                                               float* __restrict__ out) {
  __shared__ float red[512];
  const int bid = blockIdx.x;  // 256 blocks: (b, half of K-outputs)
  const int b = bid >> 1;
  const int ko0 = (bid & 1) * 128;
  const int o = threadIdx.x & 127;
  const int kslice = threadIdx.x >> 7;  // 0..3, 4-way K split
  const float* __restrict__ hr = hT + (size_t)b * CC + kslice * 256;
  const float* __restrict__ wr = Wo + (size_t)(kslice * 256) * KO + ko0 + o;
  float acc = 0.f;
#pragma unroll 8
  for (int j = 0; j < 256; ++j) acc = fmaf(hr[j], wr[(size_t)j * KO], acc);
  red[threadIdx.x] = acc;
  __syncthreads();
  if (threadIdx.x < 128) {
    out[(size_t)b * KO + ko0 + threadIdx.x] =
        (red[threadIdx.x] + red[128 + threadIdx.x]) +
        (red[256 + threadIdx.x] + red[384 + threadIdx.x]) +
        bo[ko0 + threadIdx.x];
  }
}

// ---------------------------------------------------------------------------
// Inputs (setup_inputs order): 0:x 1:n 2:d 3:h 4:a_max 5:Wg 6:bg 7:Wu 8:bu
// 9:Wa 10:Wo 11:bo.  n/d/a_max/Wa provably unused (dead state, see header).
// Coop launch preferred (guaranteed co-residency for group barriers); on ANY
// coop error, fall back to 512 single-step launches (stream-ordered, no
// barriers executed) -> correct in every environment.
// ---------------------------------------------------------------------------
extern "C" void kernel_launch(void* const* d_in, const int* in_sizes, int n_in,
                              void* d_out, int out_size, void* d_ws,
                              size_t ws_size, hipStream_t stream) {
  const float* x = (const float*)d_in[0];
  const float* h0 = (const float*)d_in[3];
  const float* Wg = (const float*)d_in[5];
  const float* bg = (const float*)d_in[6];
  const float* Wu = (const float*)d_in[7];
  const float* bu = (const float*)d_in[8];
  const float* Wo = (const float*)d_in[10];
  const float* bo = (const float*)d_in[11];
  float* out = (float*)d_out;

  float* hbuf = (float*)d_ws;  // [2][B][C] = 1 MiB
  int* cnt = (int*)((char*)d_ws + (size_t)2 * BB * CC * sizeof(float));

  hipMemsetAsync(cnt, 0, (size_t)TT * 8 * sizeof(int), stream);
  rwa_init<<<dim3(NBLK), dim3(NTHR), 0, stream>>>(h0, hbuf);

  int t0 = 0, t1 = TT;
  void* args[] = {(void*)&x,  (void*)&Wg,   (void*)&bg,  (void*)&Wu,
                  (void*)&bu, (void*)&hbuf, (void*)&cnt, (void*)&t0,
                  (void*)&t1};
  hipError_t e = hipLaunchCooperativeKernel((void*)rwa_steps, dim3(NBLK),
                                            dim3(NTHR), args, 0, stream);
  if (e != hipSuccess) {
    (void)hipGetLastError();  // clear sticky error
    for (int t = 0; t < TT; ++t) {
      hipLaunchKernelGGL(rwa_steps, dim3(NBLK), dim3(NTHR), 0, stream, x, Wg,
                         bg, Wu, bu, hbuf, cnt, t, t + 1);
    }
  }

  rwa_out<<<dim3(NBLK), dim3(512), 0, stream>>>(hbuf, Wo, bo, out);
}